// Round 11
// baseline (142.208 us; speedup 1.0000x reference)
//
#include <hip/hip_runtime.h>
#include <math.h>

#define N_NODES 100000
#define N_EDGES 1000000
#define F_IN 64
#define HID 128
#define C2 256
#define ZT 1563               // 64-node tiles
#define ZGRID 768             // zpass blocks (= Spart rows)
#define FB 64                 // finalize_a blocks
#define YGRID 256
// histogram count path
#define RANGES 4
#define RSIZE 25000
#define BPR 64
#define EPB (N_EDGES / BPR)   // 15625

typedef unsigned int uint32;
typedef __bf16 bf16x8 __attribute__((ext_vector_type(8)));
typedef float f32x4 __attribute__((ext_vector_type(4)));
typedef unsigned short ushort8v __attribute__((ext_vector_type(8)));

// ---- bf16 helpers (RNE) ----
__device__ __forceinline__ unsigned short bf_top(float f) {
  union { float f; uint32 u; } c; c.f = f;
  c.u = c.u + 0x7fffu + ((c.u >> 16) & 1u);
  return (unsigned short)(c.u >> 16);
}

// ---- int8 dot4 (HW if available) ----
#if defined(__has_builtin)
#if __has_builtin(__builtin_amdgcn_sdot4)
#define SDOT4(a, b, c) __builtin_amdgcn_sdot4((int)(a), (int)(b), (c), false)
#endif
#endif
#ifndef SDOT4
__device__ __forceinline__ int sdot4_sw(uint32 a, uint32 b, int c) {
#pragma unroll
  for (int k = 0; k < 4; ++k)
    c += (int)(signed char)(a >> (8 * k)) * (int)(signed char)(b >> (8 * k));
  return c;
}
#define SDOT4(a, b, c) sdot4_sw(a, b, c)
#endif

// ---------------- counts via LDS histograms (no global atomics) ------------
__global__ __launch_bounds__(1024) void hist_kernel(const int* __restrict__ ei,
                                                    uint32* __restrict__ Part) {
  __shared__ uint32 h[RSIZE];  // ~97.7 KB
  int range = blockIdx.x / BPR, blk = blockIdx.x % BPR;
  int lo = range * RSIZE, hi = lo + RSIZE;
  for (int i = threadIdx.x; i < RSIZE; i += 1024) h[i] = 0;
  __syncthreads();
  int e0 = blk * EPB;
  for (int e = e0 + threadIdx.x; e < e0 + EPB; e += 1024) {
    int i = ei[e], j = ei[N_EDGES + e];
    if (i >= lo && i < hi) atomicAdd(&h[i - lo], 1u);
    if (j >= lo && j < hi) atomicAdd(&h[j - lo], 0x10000u);
  }
  __syncthreads();
  uint32* p = Part + (size_t)blockIdx.x * RSIZE;
  for (int i = threadIdx.x; i < RSIZE; i += 1024) p[i] = h[i];
}

// ----------- MFMA zpass: Zfrag = relu(bf16(x)@bf16(W1)+b1), weighted stats --
// Count reduction fused: reads Part directly (creduce kernel eliminated).
__global__ __launch_bounds__(256) void zpass_kernel(const float* __restrict__ x,
                                                    const float* __restrict__ W1,
                                                    const float* __restrict__ b1,
                                                    const uint32* __restrict__ Part,
                                                    uint4* __restrict__ Zfrag,
                                                    float* __restrict__ Spart) {
  __shared__ __align__(16) unsigned short zstage[8192];  // 16 KB frag staging
  __shared__ uint32 cbuf[256];                           // count partials
  float* red = (float*)zstage;                           // 8 KB reuse after loop
  int tid = threadIdx.x;
  int l = tid & 63, w = tid >> 6;
  int lr = l & 15, lg = l >> 4;
  int cd = tid & 63, cq = tid >> 6;  // count-reduce assignment
  bf16x8 Bf[8][2];
  float b1v[8];
#pragma unroll
  for (int cb = 0; cb < 8; ++cb) {
    int col = cb * 16 + lr;
    b1v[cb] = b1[col];
#pragma unroll
    for (int kc = 0; kc < 2; ++kc) {
      union { ushort8v u; bf16x8 b; } cv;
#pragma unroll
      for (int j = 0; j < 8; ++j) cv.u[j] = bf_top(W1[(kc * 32 + lg * 8 + j) * HID + col]);
      Bf[cb][kc] = cv.b;
    }
  }
  float s10[8] = {}, s20[8] = {}, s11[8] = {}, s21[8] = {};
  for (int t = blockIdx.x; t < ZT; t += ZGRID) {
    int nbase = t * 64;
    int row = nbase + w * 16 + lr;
    bool ok = row < N_NODES;
    bf16x8 A[2];
#pragma unroll
    for (int kc = 0; kc < 2; ++kc) {
      float4 x0 = make_float4(0.f, 0.f, 0.f, 0.f), x1 = x0;
      if (ok) {
        x0 = *(const float4*)&x[(size_t)row * F_IN + kc * 32 + lg * 8];
        x1 = *(const float4*)&x[(size_t)row * F_IN + kc * 32 + lg * 8 + 4];
      }
      union { ushort8v u; bf16x8 b; } cv;
      cv.u[0] = bf_top(x0.x); cv.u[1] = bf_top(x0.y); cv.u[2] = bf_top(x0.z); cv.u[3] = bf_top(x0.w);
      cv.u[4] = bf_top(x1.x); cv.u[5] = bf_top(x1.y); cv.u[6] = bf_top(x1.z); cv.u[7] = bf_top(x1.w);
      A[kc] = cv.b;
    }
    // fused count partial: lane cd covers node nbase+cd, quarter cq sums 16 b's
    uint32 cs = 0;
    int nd = nbase + cd;
    if (nd < N_NODES) {
      int range = nd / RSIZE, ii = nd - range * RSIZE;
      const uint32* pp = Part + ((size_t)range * BPR) * RSIZE + ii;
#pragma unroll
      for (int b = cq * 16; b < cq * 16 + 16; ++b) cs += pp[(size_t)b * RSIZE];
    }
    cbuf[cq * 64 + cd] = cs;
    __syncthreads();  // prev copy-out done (zstage) + cbuf visible
    float cc0[4], cc1[4];
#pragma unroll
    for (int r = 0; r < 4; ++r) {
      int rr = w * 16 + lg * 4 + r;  // row within tile
      uint32 c01 = cbuf[rr] + cbuf[64 + rr] + cbuf[128 + rr] + cbuf[192 + rr];
      cc0[r] = (float)(c01 & 0xffffu);
      cc1[r] = (float)(c01 >> 16);
    }
#pragma unroll
    for (int cb = 0; cb < 8; ++cb) {
      f32x4 acc = {0.f, 0.f, 0.f, 0.f};
      acc = __builtin_amdgcn_mfma_f32_16x16x32_bf16(A[0], Bf[cb][0], acc, 0, 0, 0);
      acc = __builtin_amdgcn_mfma_f32_16x16x32_bf16(A[1], Bf[cb][1], acc, 0, 0, 0);
      int ks = cb >> 1;
      int lamb = ((cb & 1) * 2 + (lr >> 3)) * 16;
#pragma unroll
      for (int r = 0; r < 4; ++r) {
        float z = fmaxf(acc[r] + b1v[cb], 0.f);
        s10[cb] = fmaf(cc0[r], z, s10[cb]);
        s20[cb] = fmaf(cc0[r] * z, z, s20[cb]);
        s11[cb] = fmaf(cc1[r], z, s11[cb]);
        s21[cb] = fmaf(cc1[r] * z, z, s21[cb]);
        int zi = (w * 4 + ks) * 512 + (lamb + lg * 4 + r) * 8 + (lr & 7);
        zi ^= ((zi >> 7) & 1) << 4;
        zstage[zi] = bf_top(z);
      }
    }
    __syncthreads();  // all cbuf reads + zstage writes done
    const uint4* zs4 = (const uint4*)zstage;
    for (int i = tid; i < 1024; i += 256) {
      int si = i ^ (((i >> 4) & 1) << 1);
      Zfrag[(size_t)t * 1024 + i] = zs4[si];
    }
  }
  __syncthreads();
#pragma unroll
  for (int cb = 0; cb < 8; ++cb) {
    float a = s10[cb]; a += __shfl_xor(a, 16); a += __shfl_xor(a, 32);
    float b = s20[cb]; b += __shfl_xor(b, 16); b += __shfl_xor(b, 32);
    float c = s11[cb]; c += __shfl_xor(c, 16); c += __shfl_xor(c, 32);
    float d = s21[cb]; d += __shfl_xor(d, 16); d += __shfl_xor(d, 32);
    if (lg == 0) {
      int feat = cb * 16 + lr;
      red[(w * 4 + 0) * 128 + feat] = a;
      red[(w * 4 + 1) * 128 + feat] = b;
      red[(w * 4 + 2) * 128 + feat] = c;
      red[(w * 4 + 3) * 128 + feat] = d;
    }
  }
  __syncthreads();
  for (int o = tid; o < 512; o += 256) {
    int stat = o >> 7, feat = o & 127;
    float s = red[(0 * 4 + stat) * 128 + feat] + red[(1 * 4 + stat) * 128 + feat] +
              red[(2 * 4 + stat) * 128 + feat] + red[(3 * 4 + stat) * 128 + feat];
    Spart[(size_t)blockIdx.x * 512 + o] = s;
  }
}

// ------------------------------------- two-stage deterministic stat reduce
__global__ __launch_bounds__(512) void finalize_a(const float* __restrict__ Spart,
                                                  float* __restrict__ S2) {
  int t = threadIdx.x, b = blockIdx.x;
  float s = 0.f;
  for (int p = b; p < ZGRID; p += FB) s += Spart[(size_t)p * 512 + t];
  S2[(size_t)b * 512 + t] = s;
}

__global__ __launch_bounds__(512) void finalize_b(const float* __restrict__ S2,
                                                  const float* __restrict__ gamma,
                                                  const float* __restrict__ beta,
                                                  const float* __restrict__ W2,
                                                  const float* __restrict__ b2,
                                                  float* __restrict__ q,
                                                  unsigned short* __restrict__ Wct) {
  __shared__ float S[512];
  __shared__ float sh[256];
  __shared__ float scs[256];
  int t = threadIdx.x;
  float s = 0.f;
  for (int b = 0; b < FB; ++b) s += S2[(size_t)b * 512 + t];
  S[t] = s;
  __syncthreads();
  if (t < 128) {
    const float invE = 1.0f / (float)N_EDGES;
    float mu0 = S[t] * invE;
    float v0 = fmaxf(S[128 + t] * invE - mu0 * mu0, 0.f);
    float sc0 = gamma[t] * rsqrtf(v0 + 1e-5f);
    scs[t] = sc0;
    sh[t] = beta[t] - mu0 * sc0;
    float mu1 = S[256 + t] * invE;
    float v1 = fmaxf(S[384 + t] * invE - mu1 * mu1, 0.f);
    float sc1 = gamma[t] * rsqrtf(v1 + 1e-5f);
    scs[128 + t] = sc1;
    sh[128 + t] = beta[t] - mu1 * sc1;
  }
  __syncthreads();
  if (t < 256) {
    int side = t >> 7, c = t & 127;
    float acc = b2[c];
    for (int ff = 0; ff < HID; ++ff) acc = fmaf(sh[side * 128 + ff], W2[ff * HID + c], acc);
    q[t] = acc;
  }
  for (int i = t; i < C2 * HID; i += 512) {
    int col = i >> 7, k = i & 127;
    int side = col >> 7, c = col & 127;
    float v = W2[k * HID + c] * scs[side * 128 + k];
    Wct[(col * HID + k) ^ ((col & 7) << 3)] = bf_top(v);
  }
}

// ---- MFMA ygemm: Yq(int8, per-row-side scaled) = Zfrag @ Wc + q; g = 1/||q|| ----
__global__ __launch_bounds__(512, 2) void ygemm_kernel(const uint4* __restrict__ Zfrag,
                                                       const unsigned short* __restrict__ Wct,
                                                       const float* __restrict__ q,
                                                       uint32* __restrict__ Yq,
                                                       float* __restrict__ g0o,
                                                       float* __restrict__ g1o) {
  __shared__ float maxb[256];
  __shared__ int sqb[256];
  int tid = threadIdx.x;
  int l = tid & 63, w = tid >> 6;
  int lr = l & 15, lg = l >> 4;
  int rg = w & 1, cg = w >> 1;
  int side = cg >> 1, cgl = cg & 1;
  bf16x8 Bf[4][4];
  float qv[4];
#pragma unroll
  for (int cb = 0; cb < 4; ++cb) {
    int col = (cg * 4 + cb) * 16 + lr;
    qv[cb] = q[col];
#pragma unroll
    for (int ks = 0; ks < 4; ++ks) {
      int idx = (col * HID + ks * 32 + lg * 8) ^ ((col & 7) << 3);
      Bf[cb][ks] = *(const bf16x8*)&Wct[idx];
    }
  }
  int t = blockIdx.x;
  uint4 Ac[8];
  if (t < ZT) {
#pragma unroll
    for (int u = 0; u < 8; ++u) Ac[u] = Zfrag[((size_t)t * 16 + rg * 8 + u) * 64 + l];
  }
  for (; t < ZT; t += YGRID) {
    int nbase = t * 64;
    int tn = t + YGRID;
    uint4 An[8];
    if (tn < ZT) {
#pragma unroll
      for (int u = 0; u < 8; ++u) An[u] = Zfrag[((size_t)tn * 16 + rg * 8 + u) * 64 + l];
    }
    f32x4 acc[2][4] = {};
#pragma unroll
    for (int ks = 0; ks < 4; ++ks) {
      union { uint4 u; bf16x8 b; } A0, A1;
      A0.u = Ac[ks];
      A1.u = Ac[4 + ks];
#pragma unroll
      for (int cb = 0; cb < 4; ++cb) {
        acc[0][cb] = __builtin_amdgcn_mfma_f32_16x16x32_bf16(A0.b, Bf[cb][ks], acc[0][cb], 0, 0, 0);
        acc[1][cb] = __builtin_amdgcn_mfma_f32_16x16x32_bf16(A1.b, Bf[cb][ks], acc[1][cb], 0, 0, 0);
      }
    }
    // --- epilogue: bias, per-(row,side) absmax ---
    float ym[2][4];
#pragma unroll
    for (int nh = 0; nh < 2; ++nh)
#pragma unroll
      for (int r = 0; r < 4; ++r) {
        float m = 0.f;
#pragma unroll
        for (int cb = 0; cb < 4; ++cb) {
          float y = acc[nh][cb][r] + qv[cb];
          acc[nh][cb][r] = y;
          m = fmaxf(m, fabsf(y));
        }
#pragma unroll
        for (int s = 1; s <= 8; s <<= 1) m = fmaxf(m, __shfl_xor(m, s));
        ym[nh][r] = m;
      }
    if (lr == 0) {
#pragma unroll
      for (int nh = 0; nh < 2; ++nh)
#pragma unroll
        for (int r = 0; r < 4; ++r) maxb[w * 32 + nh * 16 + lg * 4 + r] = ym[nh][r];
    }
    __syncthreads();
    // --- combined max -> quantize, pack, write; Σq² partials ---
    int sqi[2][4];
    uint32 qpack[2][4];
#pragma unroll
    for (int nh = 0; nh < 2; ++nh)
#pragma unroll
      for (int r = 0; r < 4; ++r) {
        int ro = nh * 16 + lg * 4 + r;
        float cmax = fmaxf(maxb[(side * 4 + rg) * 32 + ro], maxb[(side * 4 + rg + 2) * 32 + ro]);
        float inv = cmax > 0.f ? 127.f / cmax : 0.f;
        int ssum = 0;
        uint32 pk = 0;
#pragma unroll
        for (int cb = 0; cb < 4; ++cb) {
          int qi = (int)rintf(acc[nh][cb][r] * inv);
          ssum += qi * qi;
          pk |= ((uint32)(qi & 0xff)) << (8 * cb);
        }
        sqi[nh][r] = ssum;
        qpack[nh][r] = pk;
      }
#pragma unroll
    for (int nh = 0; nh < 2; ++nh)
#pragma unroll
      for (int r = 0; r < 4; ++r) {
        int grow = nbase + rg * 32 + nh * 16 + lg * 4 + r;
        if (grow < N_NODES)
          Yq[(size_t)grow * 64 + side * 32 + cgl * 16 + lr] = qpack[nh][r];
      }
#pragma unroll
    for (int nh = 0; nh < 2; ++nh)
#pragma unroll
      for (int r = 0; r < 4; ++r) {
        int s = sqi[nh][r];
#pragma unroll
        for (int m = 1; m <= 8; m <<= 1) s += __shfl_xor(s, m);
        sqi[nh][r] = s;
      }
    if (lr == 0) {
#pragma unroll
      for (int nh = 0; nh < 2; ++nh)
#pragma unroll
        for (int r = 0; r < 4; ++r) sqb[w * 32 + nh * 16 + lg * 4 + r] = sqi[nh][r];
    }
    __syncthreads();
    if (tid < 128) {
      int sd = tid >> 6, row = tid & 63;
      int rg2 = row >> 5, ro = row & 31;
      int sum = sqb[(sd * 4 + rg2) * 32 + ro] + sqb[(sd * 4 + rg2 + 2) * 32 + ro];
      int grow = nbase + row;
      if (grow < N_NODES) {
        float g = sum > 0 ? rsqrtf((float)sum) : 0.f;
        (sd ? g1o : g0o)[grow] = g;
      }
    }
#pragma unroll
    for (int u = 0; u < 8; ++u) Ac[u] = An[u];
  }
}

// ---------------------------------------------------------- per-edge cosine
__global__ __launch_bounds__(256) void edge_kernel(const int* __restrict__ ei,
                                                   const uint32* __restrict__ Yq,
                                                   const float* __restrict__ g0,
                                                   const float* __restrict__ g1,
                                                   float* __restrict__ out) {
  int tid = blockIdx.x * blockDim.x + threadIdx.x;
  int g = tid >> 3, ls = tid & 7;
  int ng = (gridDim.x * blockDim.x) >> 3;
  for (int e = g; e < N_EDGES; e += ng) {
    int i = __builtin_nontemporal_load(&ei[e]);
    int j = __builtin_nontemporal_load(&ei[N_EDGES + e]);
    uint4 a = *(const uint4*)(Yq + (size_t)i * 64 + ls * 4);
    uint4 b = *(const uint4*)(Yq + (size_t)j * 64 + 32 + ls * 4);
    int d = 0;
    d = SDOT4(a.x, b.x, d);
    d = SDOT4(a.y, b.y, d);
    d = SDOT4(a.z, b.z, d);
    d = SDOT4(a.w, b.w, d);
    d += __shfl_xor(d, 1);
    d += __shfl_xor(d, 2);
    d += __shfl_xor(d, 4);
    if (ls == 0) {
      __builtin_nontemporal_store(fmaf((float)d * g0[i] * g1[j], 0.5f, 0.5f), &out[e]);
    }
  }
}

// ------------------------------------------------------------------ launch
extern "C" void kernel_launch(void* const* d_in, const int* in_sizes, int n_in,
                              void* d_out, int out_size, void* d_ws, size_t ws_size,
                              hipStream_t stream) {
  const float* x = (const float*)d_in[0];
  const int* ei = (const int*)d_in[1];
  const float* W1 = (const float*)d_in[2];
  const float* b1 = (const float*)d_in[3];
  const float* gamma = (const float*)d_in[4];
  const float* beta = (const float*)d_in[5];
  const float* W2 = (const float*)d_in[6];
  const float* b2 = (const float*)d_in[7];
  float* out = (float*)d_out;

  auto align = [](size_t v) { return (v + 255) & ~(size_t)255; };
  char* ws = (char*)d_ws;
  size_t o_part = 0;
  size_t o_sp = o_part + align((size_t)RANGES * BPR * RSIZE * sizeof(uint32));
  size_t o_s2 = o_sp + align((size_t)ZGRID * 512 * sizeof(float));
  size_t o_q = o_s2 + align((size_t)FB * 512 * sizeof(float));
  size_t o_wct = o_q + align(C2 * sizeof(float));
  size_t o_g0 = o_wct + align((size_t)C2 * HID * sizeof(unsigned short));
  size_t o_g1 = o_g0 + align(N_NODES * sizeof(float));
  size_t o_Z = o_g1 + align(N_NODES * sizeof(float));
  size_t o_Y = o_Z + align((size_t)ZT * 1024 * sizeof(uint4));

  uint32* Part = (uint32*)(ws + o_part);
  float* Sp = (float*)(ws + o_sp);
  float* S2 = (float*)(ws + o_s2);
  float* q = (float*)(ws + o_q);
  unsigned short* Wct = (unsigned short*)(ws + o_wct);
  float* g0 = (float*)(ws + o_g0);
  float* g1 = (float*)(ws + o_g1);
  uint4* Zfrag = (uint4*)(ws + o_Z);
  uint32* Yq = (uint32*)(ws + o_Y);

  hist_kernel<<<RANGES * BPR, 1024, 0, stream>>>(ei, Part);
  zpass_kernel<<<ZGRID, 256, 0, stream>>>(x, W1, b1, Part, Zfrag, Sp);
  finalize_a<<<FB, 512, 0, stream>>>(Sp, S2);
  finalize_b<<<1, 512, 0, stream>>>(S2, gamma, beta, W2, b2, q, Wct);
  ygemm_kernel<<<YGRID, 512, 0, stream>>>(Zfrag, Wct, q, Yq, g0, g1);
  edge_kernel<<<2048, 256, 0, stream>>>(ei, Yq, g0, g1, out);
}

// Round 12
// 136.189 us; speedup vs baseline: 1.0442x; 1.0442x over previous
//
#include <hip/hip_runtime.h>
#include <math.h>

#define N_NODES 100000
#define N_EDGES 1000000
#define F_IN 64
#define HID 128
#define C2 256
#define ZT 1563               // 64-node tiles
#define ZGRID 512             // zpass blocks (= Spart rows)
#define FB 64                 // finalize_a blocks
#define YGRID 512
// histogram count path
#define RANGES 4
#define RSIZE 25000
#define BPR 64
#define EPB (N_EDGES / BPR)   // 15625

typedef unsigned int uint32;
typedef __bf16 bf16x8 __attribute__((ext_vector_type(8)));
typedef float f32x4 __attribute__((ext_vector_type(4)));
typedef unsigned short ushort8v __attribute__((ext_vector_type(8)));

// ---- bf16 helpers (RNE) ----
__device__ __forceinline__ unsigned short bf_top(float f) {
  union { float f; uint32 u; } c; c.f = f;
  c.u = c.u + 0x7fffu + ((c.u >> 16) & 1u);
  return (unsigned short)(c.u >> 16);
}

// ---- int8 dot4 (HW if available) ----
#if defined(__has_builtin)
#if __has_builtin(__builtin_amdgcn_sdot4)
#define SDOT4(a, b, c) __builtin_amdgcn_sdot4((int)(a), (int)(b), (c), false)
#endif
#endif
#ifndef SDOT4
__device__ __forceinline__ int sdot4_sw(uint32 a, uint32 b, int c) {
#pragma unroll
  for (int k = 0; k < 4; ++k)
    c += (int)(signed char)(a >> (8 * k)) * (int)(signed char)(b >> (8 * k));
  return c;
}
#define SDOT4(a, b, c) sdot4_sw(a, b, c)
#endif

// ---------------- counts via LDS histograms (no global atomics) ------------
__global__ __launch_bounds__(1024) void hist_kernel(const int* __restrict__ ei,
                                                    uint32* __restrict__ Part) {
  __shared__ uint32 h[RSIZE];  // ~97.7 KB
  int range = blockIdx.x / BPR, blk = blockIdx.x % BPR;
  int lo = range * RSIZE, hi = lo + RSIZE;
  for (int i = threadIdx.x; i < RSIZE; i += 1024) h[i] = 0;
  __syncthreads();
  int e0 = blk * EPB;
  for (int e = e0 + threadIdx.x; e < e0 + EPB; e += 1024) {
    int i = ei[e], j = ei[N_EDGES + e];
    if (i >= lo && i < hi) atomicAdd(&h[i - lo], 1u);
    if (j >= lo && j < hi) atomicAdd(&h[j - lo], 0x10000u);
  }
  __syncthreads();
  uint32* p = Part + (size_t)blockIdx.x * RSIZE;
  for (int i = threadIdx.x; i < RSIZE; i += 1024) p[i] = h[i];
}

__global__ __launch_bounds__(256) void creduce_kernel(const uint32* __restrict__ Part,
                                                      float* __restrict__ c0f,
                                                      float* __restrict__ c1f) {
  int n = blockIdx.x * 256 + threadIdx.x;
  if (n >= N_NODES) return;
  int range = n / RSIZE, i = n - range * RSIZE;
  const uint32* p = Part + (size_t)range * BPR * RSIZE + i;
  uint32 s = 0;
#pragma unroll 8
  for (int b = 0; b < BPR; ++b) s += p[(size_t)b * RSIZE];
  c0f[n] = (float)(s & 0xffffu);
  c1f[n] = (float)(s >> 16);
}

// ----------- MFMA zpass: Zfrag = relu(bf16(x)@bf16(W1)+b1), weighted stats --
// NOTE: no min-waves in launch_bounds — (256,3) in R9 capped VGPR at 84 and
// spilled the stat accumulators (+34 MB scratch traffic, 2.6x slower).
// NOTE (R11): fusing creduce in here regressed (extra per-tile sync on the
// critical path) — keep the standalone creduce kernel.
__global__ __launch_bounds__(256) void zpass_kernel(const float* __restrict__ x,
                                                    const float* __restrict__ W1,
                                                    const float* __restrict__ b1,
                                                    const float* __restrict__ c0f,
                                                    const float* __restrict__ c1f,
                                                    uint4* __restrict__ Zfrag,
                                                    float* __restrict__ Spart) {
  __shared__ __align__(16) unsigned short zstage[8192];  // 16 KB frag staging
  float* red = (float*)zstage;                           // 8 KB reuse after loop
  int tid = threadIdx.x;
  int l = tid & 63, w = tid >> 6;
  int lr = l & 15, lg = l >> 4;
  bf16x8 Bf[8][2];
  float b1v[8];
#pragma unroll
  for (int cb = 0; cb < 8; ++cb) {
    int col = cb * 16 + lr;
    b1v[cb] = b1[col];
#pragma unroll
    for (int kc = 0; kc < 2; ++kc) {
      union { ushort8v u; bf16x8 b; } cv;
#pragma unroll
      for (int j = 0; j < 8; ++j) cv.u[j] = bf_top(W1[(kc * 32 + lg * 8 + j) * HID + col]);
      Bf[cb][kc] = cv.b;
    }
  }
  float s10[8] = {}, s20[8] = {}, s11[8] = {}, s21[8] = {};
  for (int t = blockIdx.x; t < ZT; t += ZGRID) {
    int nbase = t * 64;
    int row = nbase + w * 16 + lr;
    bool ok = row < N_NODES;
    bf16x8 A[2];
#pragma unroll
    for (int kc = 0; kc < 2; ++kc) {
      float4 x0 = make_float4(0.f, 0.f, 0.f, 0.f), x1 = x0;
      if (ok) {
        x0 = *(const float4*)&x[(size_t)row * F_IN + kc * 32 + lg * 8];
        x1 = *(const float4*)&x[(size_t)row * F_IN + kc * 32 + lg * 8 + 4];
      }
      union { ushort8v u; bf16x8 b; } cv;
      cv.u[0] = bf_top(x0.x); cv.u[1] = bf_top(x0.y); cv.u[2] = bf_top(x0.z); cv.u[3] = bf_top(x0.w);
      cv.u[4] = bf_top(x1.x); cv.u[5] = bf_top(x1.y); cv.u[6] = bf_top(x1.z); cv.u[7] = bf_top(x1.w);
      A[kc] = cv.b;
    }
    float cc0[4], cc1[4];
#pragma unroll
    for (int r = 0; r < 4; ++r) {
      int node = nbase + w * 16 + lg * 4 + r;
      bool okr = node < N_NODES;
      cc0[r] = okr ? c0f[node] : 0.f;
      cc1[r] = okr ? c1f[node] : 0.f;
    }
    __syncthreads();
#pragma unroll
    for (int cb = 0; cb < 8; ++cb) {
      f32x4 acc = {0.f, 0.f, 0.f, 0.f};
      acc = __builtin_amdgcn_mfma_f32_16x16x32_bf16(A[0], Bf[cb][0], acc, 0, 0, 0);
      acc = __builtin_amdgcn_mfma_f32_16x16x32_bf16(A[1], Bf[cb][1], acc, 0, 0, 0);
      int ks = cb >> 1;
      int lamb = ((cb & 1) * 2 + (lr >> 3)) * 16;
#pragma unroll
      for (int r = 0; r < 4; ++r) {
        float z = fmaxf(acc[r] + b1v[cb], 0.f);
        s10[cb] = fmaf(cc0[r], z, s10[cb]);
        s20[cb] = fmaf(cc0[r] * z, z, s20[cb]);
        s11[cb] = fmaf(cc1[r], z, s11[cb]);
        s21[cb] = fmaf(cc1[r] * z, z, s21[cb]);
        int zi = (w * 4 + ks) * 512 + (lamb + lg * 4 + r) * 8 + (lr & 7);
        zi ^= ((zi >> 7) & 1) << 4;
        zstage[zi] = bf_top(z);
      }
    }
    __syncthreads();
    const uint4* zs4 = (const uint4*)zstage;
    for (int i = tid; i < 1024; i += 256) {
      int si = i ^ (((i >> 4) & 1) << 1);
      Zfrag[(size_t)t * 1024 + i] = zs4[si];
    }
  }
  __syncthreads();
#pragma unroll
  for (int cb = 0; cb < 8; ++cb) {
    float a = s10[cb]; a += __shfl_xor(a, 16); a += __shfl_xor(a, 32);
    float b = s20[cb]; b += __shfl_xor(b, 16); b += __shfl_xor(b, 32);
    float c = s11[cb]; c += __shfl_xor(c, 16); c += __shfl_xor(c, 32);
    float d = s21[cb]; d += __shfl_xor(d, 16); d += __shfl_xor(d, 32);
    if (lg == 0) {
      int feat = cb * 16 + lr;
      red[(w * 4 + 0) * 128 + feat] = a;
      red[(w * 4 + 1) * 128 + feat] = b;
      red[(w * 4 + 2) * 128 + feat] = c;
      red[(w * 4 + 3) * 128 + feat] = d;
    }
  }
  __syncthreads();
  for (int o = tid; o < 512; o += 256) {
    int stat = o >> 7, feat = o & 127;
    float s = red[(0 * 4 + stat) * 128 + feat] + red[(1 * 4 + stat) * 128 + feat] +
              red[(2 * 4 + stat) * 128 + feat] + red[(3 * 4 + stat) * 128 + feat];
    Spart[(size_t)blockIdx.x * 512 + o] = s;
  }
}

// ------------------------------------- two-stage deterministic stat reduce
__global__ __launch_bounds__(512) void finalize_a(const float* __restrict__ Spart,
                                                  float* __restrict__ S2) {
  int t = threadIdx.x, b = blockIdx.x;
  float s = 0.f;
  for (int p = b; p < ZGRID; p += FB) s += Spart[(size_t)p * 512 + t];
  S2[(size_t)b * 512 + t] = s;
}

__global__ __launch_bounds__(512) void finalize_b(const float* __restrict__ S2,
                                                  const float* __restrict__ gamma,
                                                  const float* __restrict__ beta,
                                                  const float* __restrict__ W2,
                                                  const float* __restrict__ b2,
                                                  float* __restrict__ q,
                                                  unsigned short* __restrict__ Wct) {
  __shared__ float S[512];
  __shared__ float sh[256];
  __shared__ float scs[256];
  int t = threadIdx.x;
  float s = 0.f;
  for (int b = 0; b < FB; ++b) s += S2[(size_t)b * 512 + t];
  S[t] = s;
  __syncthreads();
  if (t < 128) {
    const float invE = 1.0f / (float)N_EDGES;
    float mu0 = S[t] * invE;
    float v0 = fmaxf(S[128 + t] * invE - mu0 * mu0, 0.f);
    float sc0 = gamma[t] * rsqrtf(v0 + 1e-5f);
    scs[t] = sc0;
    sh[t] = beta[t] - mu0 * sc0;
    float mu1 = S[256 + t] * invE;
    float v1 = fmaxf(S[384 + t] * invE - mu1 * mu1, 0.f);
    float sc1 = gamma[t] * rsqrtf(v1 + 1e-5f);
    scs[128 + t] = sc1;
    sh[128 + t] = beta[t] - mu1 * sc1;
  }
  __syncthreads();
  if (t < 256) {
    int side = t >> 7, c = t & 127;
    float acc = b2[c];
    for (int ff = 0; ff < HID; ++ff) acc = fmaf(sh[side * 128 + ff], W2[ff * HID + c], acc);
    q[t] = acc;
  }
  for (int i = t; i < C2 * HID; i += 512) {
    int col = i >> 7, k = i & 127;
    int side = col >> 7, c = col & 127;
    float v = W2[k * HID + c] * scs[side * 128 + k];
    Wct[(col * HID + k) ^ ((col & 7) << 3)] = bf_top(v);
  }
}

// ---- MFMA ygemm: Yq(int8, per-row-side scaled) = Zfrag @ Wc + q; g = 1/||q|| ----
// B fragments loaded straight from the 64 KB L2-resident Wct (no LDS staging).
__global__ __launch_bounds__(512, 2) void ygemm_kernel(const uint4* __restrict__ Zfrag,
                                                       const unsigned short* __restrict__ Wct,
                                                       const float* __restrict__ q,
                                                       uint32* __restrict__ Yq,
                                                       float* __restrict__ g0o,
                                                       float* __restrict__ g1o) {
  __shared__ float maxb[256];
  __shared__ int sqb[256];
  int tid = threadIdx.x;
  int l = tid & 63, w = tid >> 6;
  int lr = l & 15, lg = l >> 4;
  int rg = w & 1, cg = w >> 1;
  int side = cg >> 1, cgl = cg & 1;
  bf16x8 Bf[4][4];
  float qv[4];
#pragma unroll
  for (int cb = 0; cb < 4; ++cb) {
    int col = (cg * 4 + cb) * 16 + lr;
    qv[cb] = q[col];
#pragma unroll
    for (int ks = 0; ks < 4; ++ks) {
      int idx = (col * HID + ks * 32 + lg * 8) ^ ((col & 7) << 3);
      Bf[cb][ks] = *(const bf16x8*)&Wct[idx];
    }
  }
  int t = blockIdx.x;
  uint4 Ac[8];
  if (t < ZT) {
#pragma unroll
    for (int u = 0; u < 8; ++u) Ac[u] = Zfrag[((size_t)t * 16 + rg * 8 + u) * 64 + l];
  }
  for (; t < ZT; t += YGRID) {
    int nbase = t * 64;
    int tn = t + YGRID;
    uint4 An[8];
    if (tn < ZT) {
#pragma unroll
      for (int u = 0; u < 8; ++u) An[u] = Zfrag[((size_t)tn * 16 + rg * 8 + u) * 64 + l];
    }
    f32x4 acc[2][4] = {};
#pragma unroll
    for (int ks = 0; ks < 4; ++ks) {
      union { uint4 u; bf16x8 b; } A0, A1;
      A0.u = Ac[ks];
      A1.u = Ac[4 + ks];
#pragma unroll
      for (int cb = 0; cb < 4; ++cb) {
        acc[0][cb] = __builtin_amdgcn_mfma_f32_16x16x32_bf16(A0.b, Bf[cb][ks], acc[0][cb], 0, 0, 0);
        acc[1][cb] = __builtin_amdgcn_mfma_f32_16x16x32_bf16(A1.b, Bf[cb][ks], acc[1][cb], 0, 0, 0);
      }
    }
    // --- epilogue: bias, per-(row,side) absmax ---
    float ym[2][4];
#pragma unroll
    for (int nh = 0; nh < 2; ++nh)
#pragma unroll
      for (int r = 0; r < 4; ++r) {
        float m = 0.f;
#pragma unroll
        for (int cb = 0; cb < 4; ++cb) {
          float y = acc[nh][cb][r] + qv[cb];
          acc[nh][cb][r] = y;
          m = fmaxf(m, fabsf(y));
        }
#pragma unroll
        for (int s = 1; s <= 8; s <<= 1) m = fmaxf(m, __shfl_xor(m, s));
        ym[nh][r] = m;
      }
    if (lr == 0) {
#pragma unroll
      for (int nh = 0; nh < 2; ++nh)
#pragma unroll
        for (int r = 0; r < 4; ++r) maxb[w * 32 + nh * 16 + lg * 4 + r] = ym[nh][r];
    }
    __syncthreads();
    // --- combined max -> quantize, pack, write; Σq² partials ---
    int sqi[2][4];
    uint32 qpack[2][4];
#pragma unroll
    for (int nh = 0; nh < 2; ++nh)
#pragma unroll
      for (int r = 0; r < 4; ++r) {
        int ro = nh * 16 + lg * 4 + r;
        float cmax = fmaxf(maxb[(side * 4 + rg) * 32 + ro], maxb[(side * 4 + rg + 2) * 32 + ro]);
        float inv = cmax > 0.f ? 127.f / cmax : 0.f;
        int ssum = 0;
        uint32 pk = 0;
#pragma unroll
        for (int cb = 0; cb < 4; ++cb) {
          int qi = (int)rintf(acc[nh][cb][r] * inv);
          ssum += qi * qi;
          pk |= ((uint32)(qi & 0xff)) << (8 * cb);
        }
        sqi[nh][r] = ssum;
        qpack[nh][r] = pk;
      }
#pragma unroll
    for (int nh = 0; nh < 2; ++nh)
#pragma unroll
      for (int r = 0; r < 4; ++r) {
        int grow = nbase + rg * 32 + nh * 16 + lg * 4 + r;
        if (grow < N_NODES)
          Yq[(size_t)grow * 64 + side * 32 + cgl * 16 + lr] = qpack[nh][r];
      }
#pragma unroll
    for (int nh = 0; nh < 2; ++nh)
#pragma unroll
      for (int r = 0; r < 4; ++r) {
        int s = sqi[nh][r];
#pragma unroll
        for (int m = 1; m <= 8; m <<= 1) s += __shfl_xor(s, m);
        sqi[nh][r] = s;
      }
    if (lr == 0) {
#pragma unroll
      for (int nh = 0; nh < 2; ++nh)
#pragma unroll
        for (int r = 0; r < 4; ++r) sqb[w * 32 + nh * 16 + lg * 4 + r] = sqi[nh][r];
    }
    __syncthreads();
    if (tid < 128) {
      int sd = tid >> 6, row = tid & 63;
      int rg2 = row >> 5, ro = row & 31;
      int sum = sqb[(sd * 4 + rg2) * 32 + ro] + sqb[(sd * 4 + rg2 + 2) * 32 + ro];
      int grow = nbase + row;
      if (grow < N_NODES) {
        float g = sum > 0 ? rsqrtf((float)sum) : 0.f;
        (sd ? g1o : g0o)[grow] = g;
      }
    }
#pragma unroll
    for (int u = 0; u < 8; ++u) Ac[u] = An[u];
  }
}

// ---------------------------------------------------------- per-edge cosine
__global__ __launch_bounds__(256) void edge_kernel(const int* __restrict__ ei,
                                                   const uint32* __restrict__ Yq,
                                                   const float* __restrict__ g0,
                                                   const float* __restrict__ g1,
                                                   float* __restrict__ out) {
  int tid = blockIdx.x * blockDim.x + threadIdx.x;
  int g = tid >> 3, ls = tid & 7;
  int ng = (gridDim.x * blockDim.x) >> 3;
  for (int e = g; e < N_EDGES; e += ng) {
    int i = __builtin_nontemporal_load(&ei[e]);
    int j = __builtin_nontemporal_load(&ei[N_EDGES + e]);
    uint4 a = *(const uint4*)(Yq + (size_t)i * 64 + ls * 4);
    uint4 b = *(const uint4*)(Yq + (size_t)j * 64 + 32 + ls * 4);
    int d = 0;
    d = SDOT4(a.x, b.x, d);
    d = SDOT4(a.y, b.y, d);
    d = SDOT4(a.z, b.z, d);
    d = SDOT4(a.w, b.w, d);
    d += __shfl_xor(d, 1);
    d += __shfl_xor(d, 2);
    d += __shfl_xor(d, 4);
    if (ls == 0) {
      __builtin_nontemporal_store(fmaf((float)d * g0[i] * g1[j], 0.5f, 0.5f), &out[e]);
    }
  }
}

// ------------------------------------------------------------------ launch
extern "C" void kernel_launch(void* const* d_in, const int* in_sizes, int n_in,
                              void* d_out, int out_size, void* d_ws, size_t ws_size,
                              hipStream_t stream) {
  const float* x = (const float*)d_in[0];
  const int* ei = (const int*)d_in[1];
  const float* W1 = (const float*)d_in[2];
  const float* b1 = (const float*)d_in[3];
  const float* gamma = (const float*)d_in[4];
  const float* beta = (const float*)d_in[5];
  const float* W2 = (const float*)d_in[6];
  const float* b2 = (const float*)d_in[7];
  float* out = (float*)d_out;

  auto align = [](size_t v) { return (v + 255) & ~(size_t)255; };
  char* ws = (char*)d_ws;
  size_t o_part = 0;
  size_t o_c0 = o_part + align((size_t)RANGES * BPR * RSIZE * sizeof(uint32));
  size_t o_c1 = o_c0 + align(N_NODES * sizeof(float));
  size_t o_sp = o_c1 + align(N_NODES * sizeof(float));
  size_t o_s2 = o_sp + align((size_t)ZGRID * 512 * sizeof(float));
  size_t o_q = o_s2 + align((size_t)FB * 512 * sizeof(float));
  size_t o_wct = o_q + align(C2 * sizeof(float));
  size_t o_g0 = o_wct + align((size_t)C2 * HID * sizeof(unsigned short));
  size_t o_g1 = o_g0 + align(N_NODES * sizeof(float));
  size_t o_Z = o_g1 + align(N_NODES * sizeof(float));
  size_t o_Y = o_Z + align((size_t)ZT * 1024 * sizeof(uint4));

  uint32* Part = (uint32*)(ws + o_part);
  float* c0f = (float*)(ws + o_c0);
  float* c1f = (float*)(ws + o_c1);
  float* Sp = (float*)(ws + o_sp);
  float* S2 = (float*)(ws + o_s2);
  float* q = (float*)(ws + o_q);
  unsigned short* Wct = (unsigned short*)(ws + o_wct);
  float* g0 = (float*)(ws + o_g0);
  float* g1 = (float*)(ws + o_g1);
  uint4* Zfrag = (uint4*)(ws + o_Z);
  uint32* Yq = (uint32*)(ws + o_Y);

  hist_kernel<<<RANGES * BPR, 1024, 0, stream>>>(ei, Part);
  creduce_kernel<<<(N_NODES + 255) / 256, 256, 0, stream>>>(Part, c0f, c1f);
  zpass_kernel<<<ZGRID, 256, 0, stream>>>(x, W1, b1, c0f, c1f, Zfrag, Sp);
  finalize_a<<<FB, 512, 0, stream>>>(Sp, S2);
  finalize_b<<<1, 512, 0, stream>>>(S2, gamma, beta, W2, b2, q, Wct);
  ygemm_kernel<<<YGRID, 512, 0, stream>>>(Zfrag, Wct, q, Yq, g0, g1);
  edge_kernel<<<2048, 256, 0, stream>>>(ei, Yq, g0, g1, out);
}